// Round 2
// baseline (307.029 us; speedup 1.0000x reference)
//
#include <hip/hip_runtime.h>
#include <math.h>

#define BB 64
#define NN 1024
#define DD 768
#define KK 8

// ws layout (floats):
//   [0, 6144)             s_norm (K x D)
//   [6144, 6144+524288)   logits [b][k][n]  (B*K*N)
//   [530432, 530496)      per-b partial ortho sums (64)
#define WS_SNORM   0
#define WS_LOGITS  6144
#define WS_PART    (6144 + 524288)

// out layout (floats):
//   [0, 393216)           slots_b  (B*K*D)
//   [393216]              ortho_loss
//   [393217, 458753)      img_space_mask (B*N)

// ---------------------------------------------------------------- kernel 1
// broadcast raw slots -> out[0..393215]. grid 1536 x 256; blockIdx = b*24 + r
__global__ void k_broadcast(const float* __restrict__ slots, float* __restrict__ out) {
    const int b = blockIdx.x / 24;
    const int r = blockIdx.x % 24;
    const int idx = r * 256 + threadIdx.x;      // 0..6143
    out[b * (KK * DD) + idx] = slots[idx];
}

// ---------------------------------------------------------------- kernel 1b
// normalize slots -> ws snorm. grid 8 x 256
__global__ void k_snorm(const float* __restrict__ slots, float* __restrict__ snorm) {
    const int k = blockIdx.x;
    const int t = threadIdx.x;
    const int lane = t & 63, wave = t >> 6;
    __shared__ float wsum[4];
    float s = 0.f;
    for (int j = t; j < DD; j += 256) {
        float v = slots[k * DD + j];
        s += v * v;
    }
#pragma unroll
    for (int off = 1; off < 64; off <<= 1) s += __shfl_xor(s, off, 64);
    if (lane == 0) wsum[wave] = s;
    __syncthreads();
    const float tot = wsum[0] + wsum[1] + wsum[2] + wsum[3];
    const float rn = 1.0f / fmaxf(sqrtf(tot), 1e-6f);
    for (int j = t; j < DD; j += 256) snorm[k * DD + j] = slots[k * DD + j] * rn;
}

// ---------------------------------------------------------------- kernel 2
// logits[b][k][n] = dot(x[b,n,:], snorm[k,:]) / max(||x_n||, eps)
// grid 1024 blocks x 256 thr; b = blk>>4, chunk = blk&15 (64 n per chunk).
// wave handles 16 consecutive n; lane owns 12 d-elements (3 x float4);
// slots live in 96 loop-invariant VGPRs. Two-level reduction:
//   stage A: butterfly xor{1,2,4} on all 9 accs  -> group-of-8 sums (27 shfl)
//   stage B: v = acc[lane&7] (7 cndmask), u = acc[8]
//   stage C: butterfly xor{8,16,32} on v,u        -> totals       (6 shfl)
__launch_bounds__(256, 2)
__global__ void k_logits(const float* __restrict__ x, const float* __restrict__ snorm,
                         float* __restrict__ logits) {
    const int b     = blockIdx.x >> 4;
    const int chunk = blockIdx.x & 15;
    const int wave  = threadIdx.x >> 6;
    const int lane  = threadIdx.x & 63;

    // loop-invariant slot fragments: sreg[k][j] = snorm[k, j*256 + lane*4 .. +3]
    float4 sreg[KK][3];
#pragma unroll
    for (int k = 0; k < KK; ++k)
#pragma unroll
        for (int j = 0; j < 3; ++j)
            sreg[k][j] = *reinterpret_cast<const float4*>(snorm + k * DD + j * 256 + lane * 4);

    const int n_base = chunk * 64 + wave * 16;

    // prologue load for i=0
    const float4* xp = reinterpret_cast<const float4*>(x + (long)(b * NN + n_base) * DD);
    float4 c0 = xp[lane], c1 = xp[64 + lane], c2 = xp[128 + lane];

    for (int i = 0; i < 16; ++i) {
        const int n = n_base + i;
        // prefetch next n while we compute current
        float4 p0, p1, p2;
        if (i < 15) {
            const float4* xq = reinterpret_cast<const float4*>(x + (long)(b * NN + n + 1) * DD);
            p0 = xq[lane]; p1 = xq[64 + lane]; p2 = xq[128 + lane];
        }

        float acc[KK + 1];
#pragma unroll
        for (int q = 0; q <= KK; ++q) acc[q] = 0.f;

#pragma unroll
        for (int k = 0; k < KK; ++k) {
            acc[k] = fmaf(c0.x, sreg[k][0].x, acc[k]);
            acc[k] = fmaf(c0.y, sreg[k][0].y, acc[k]);
            acc[k] = fmaf(c0.z, sreg[k][0].z, acc[k]);
            acc[k] = fmaf(c0.w, sreg[k][0].w, acc[k]);
            acc[k] = fmaf(c1.x, sreg[k][1].x, acc[k]);
            acc[k] = fmaf(c1.y, sreg[k][1].y, acc[k]);
            acc[k] = fmaf(c1.z, sreg[k][1].z, acc[k]);
            acc[k] = fmaf(c1.w, sreg[k][1].w, acc[k]);
            acc[k] = fmaf(c2.x, sreg[k][2].x, acc[k]);
            acc[k] = fmaf(c2.y, sreg[k][2].y, acc[k]);
            acc[k] = fmaf(c2.z, sreg[k][2].z, acc[k]);
            acc[k] = fmaf(c2.w, sreg[k][2].w, acc[k]);
        }
        // self dot for ||x||
        acc[KK] = fmaf(c0.x, c0.x, acc[KK]); acc[KK] = fmaf(c0.y, c0.y, acc[KK]);
        acc[KK] = fmaf(c0.z, c0.z, acc[KK]); acc[KK] = fmaf(c0.w, c0.w, acc[KK]);
        acc[KK] = fmaf(c1.x, c1.x, acc[KK]); acc[KK] = fmaf(c1.y, c1.y, acc[KK]);
        acc[KK] = fmaf(c1.z, c1.z, acc[KK]); acc[KK] = fmaf(c1.w, c1.w, acc[KK]);
        acc[KK] = fmaf(c2.x, c2.x, acc[KK]); acc[KK] = fmaf(c2.y, c2.y, acc[KK]);
        acc[KK] = fmaf(c2.z, c2.z, acc[KK]); acc[KK] = fmaf(c2.w, c2.w, acc[KK]);

        // stage A: intra-8 butterfly on all 9 accs (27 shuffles)
#pragma unroll
        for (int off = 1; off < 8; off <<= 1)
#pragma unroll
            for (int q = 0; q <= KK; ++q) acc[q] += __shfl_xor(acc[q], off, 64);

        // stage B: per-lane value select (static indices only)
        float v = acc[0];
#pragma unroll
        for (int q = 1; q < KK; ++q) v = ((lane & 7) == q) ? acc[q] : v;
        float u = acc[KK];

        // stage C: cross-group butterfly on v,u (6 shuffles)
#pragma unroll
        for (int off = 8; off < 64; off <<= 1) {
            v += __shfl_xor(v, off, 64);
            u += __shfl_xor(u, off, 64);
        }

        const float rn = 1.0f / fmaxf(sqrtf(u), 1e-6f);
        if (lane < KK) logits[(((b << 3) + lane) << 10) + n] = v * rn;

        c0 = p0; c1 = p1; c2 = p2;
    }
}

// ---------------------------------------------------------------- kernel 3
// per-b: top-8 thresholds, img_space_mask, exp rows, gram, ortho partial.
// grid 64 x 256
__launch_bounds__(256)
__global__ void k_select(const float* __restrict__ logits, float* __restrict__ out_mask,
                         float* __restrict__ partials) {
    const int b = blockIdx.x;
    __shared__ float lds[KK][1032];   // padded rows (stride 1032 -> bank spread)
    __shared__ float thr[KK], rmax[KK], rsum[KK];
    __shared__ float gpart[4][64];
    const int t = threadIdx.x, lane = t & 63, wave = t >> 6;

    // A: load logits[b] (8 x 1024) into LDS
    for (int f = t; f < KK * NN; f += 256) lds[f >> 10][f & 1023] = logits[b * (KK * NN) + f];
    __syncthreads();

    // B: top-8 per row via 8x argmax-extract. wave w handles rows w and w+4.
#pragma unroll
    for (int r = 0; r < 2; ++r) {
        const int k = wave + r * 4;
        float v[16];
#pragma unroll
        for (int i = 0; i < 16; ++i) v[i] = lds[k][i * 64 + lane];
        float th = 0.f, mx = -1e30f;
        for (int e = 0; e < 8; ++e) {
            float lv = -1e30f; int li = 0;
#pragma unroll
            for (int i = 0; i < 16; ++i) {
                if (v[i] > lv) { lv = v[i]; li = i * 64 + lane; }
            }
#pragma unroll
            for (int off = 1; off < 64; off <<= 1) {
                const float ov = __shfl_xor(lv, off, 64);
                const int   oi = __shfl_xor(li, off, 64);
                if (ov > lv || (ov == lv && oi < li)) { lv = ov; li = oi; }
            }
            if (e == 0) mx = lv;
            th = lv;
            // remove exactly the found instance (static indices only)
#pragma unroll
            for (int i = 0; i < 16; ++i)
                if (i * 64 + lane == li) v[i] = -1e30f;
        }
        if (lane == 0) { thr[k] = th; rmax[k] = mx; }
    }
    __syncthreads();

    // M: img_space_mask[b][n] = any_k(logit >= thr)
    for (int n = t; n < NN; n += 256) {
        float m = 0.f;
#pragma unroll
        for (int k = 0; k < KK; ++k) m = fmaxf(m, (lds[k][n] >= thr[k]) ? 1.f : 0.f);
        out_mask[b * NN + n] = m;
    }
    __syncthreads();

    // C: overwrite rows with exp(logit - rowmax) for selected, 0 otherwise; row sums.
#pragma unroll
    for (int r = 0; r < 2; ++r) {
        const int k = wave + r * 4;
        const float th = thr[k], mx = rmax[k];
        float s = 0.f;
#pragma unroll
        for (int i = 0; i < 16; ++i) {
            const int n = i * 64 + lane;
            const float lg = lds[k][n];
            const float p = (lg >= th) ? __expf(lg - mx) : 0.f;
            lds[k][n] = p;
            s += p;
        }
#pragma unroll
        for (int off = 1; off < 64; off <<= 1) s += __shfl_xor(s, off, 64);
        if (lane == 0) rsum[k] = s;
    }
    __syncthreads();

    // D: gram[k][j] = (sum_n p_k p_j) / (rsum_k rsum_j); partial ortho sum.
    {
        const int k = lane >> 3, j = lane & 7;
        float s = 0.f;
#pragma unroll 8
        for (int i = 0; i < 256; ++i) {
            const int n = (wave << 8) + i;
            s += lds[k][n] * lds[j][n];
        }
        gpart[wave][lane] = s;
    }
    __syncthreads();
    if (wave == 0) {
        const int k = lane >> 3, j = lane & 7;
        float g = gpart[0][lane] + gpart[1][lane] + gpart[2][lane] + gpart[3][lane];
        g *= (1.0f / rsum[k]) * (1.0f / rsum[j]);
        float d = fabsf(g - ((k == j) ? 1.f : 0.f));
#pragma unroll
        for (int off = 1; off < 64; off <<= 1) d += __shfl_xor(d, off, 64);
        if (lane == 0) partials[b] = d;
    }
}

// ---------------------------------------------------------------- kernel 4
__global__ void k_final(const float* __restrict__ partials, float* __restrict__ out_loss) {
    const int lane = threadIdx.x;  // 64
    float v = partials[lane];
#pragma unroll
    for (int off = 1; off < 64; off <<= 1) v += __shfl_xor(v, off, 64);
    if (lane == 0) out_loss[0] = v * (1.0f / 4096.0f);
}

extern "C" void kernel_launch(void* const* d_in, const int* in_sizes, int n_in,
                              void* d_out, int out_size, void* d_ws, size_t ws_size,
                              hipStream_t stream) {
    const float* x     = (const float*)d_in[0];   // (64,1024,768) f32
    const float* slots = (const float*)d_in[1];   // (1,8,768)     f32
    float* out = (float*)d_out;
    float* ws  = (float*)d_ws;

    float* snorm    = ws + WS_SNORM;
    float* logits   = ws + WS_LOGITS;
    float* partials = ws + WS_PART;

    float* out_slots = out;                         // 393216
    float* out_loss  = out + 393216;                // 1
    float* out_mask  = out + 393217;                // 65536

    k_broadcast<<<dim3(BB * 24), dim3(256), 0, stream>>>(slots, out_slots);
    k_snorm    <<<dim3(KK),      dim3(256), 0, stream>>>(slots, snorm);
    k_logits   <<<dim3(BB * 16), dim3(256), 0, stream>>>(x, snorm, logits);
    k_select   <<<dim3(BB),      dim3(256), 0, stream>>>(logits, out_mask, partials);
    k_final    <<<dim3(1),       dim3(64),  0, stream>>>(partials, out_loss);
}

// Round 6
// 297.884 us; speedup vs baseline: 1.0307x; 1.0307x over previous
//
#include <hip/hip_runtime.h>
#include <math.h>

#define BB 64
#define NN 1024
#define DD 768
#define KK 8

// ws layout (floats):
//   [0, 6144)             s_norm (K x D)
//   [6144, 6144+524288)   logits [b][k][n]  (B*K*N)
//   [530432, 530496)      per-b partial ortho sums (64)
#define WS_SNORM   0
#define WS_LOGITS  6144
#define WS_PART    (6144 + 524288)

// out layout (floats):
//   [0, 393216)           slots_b  (B*K*D)
//   [393216]              ortho_loss
//   [393217, 458753)      img_space_mask (B*N)

// DPP butterfly add: x += x_from(lane permuted by CTRL). VALU-only (no DS pipe).
// 0xB1 = quad_perm [1,0,3,2] (xor1), 0x4E = quad_perm [2,3,0,1] (xor2),
// 0x128 = row_ror:8 (== xor8 within a 16-lane row).
template <int CTRL>
__device__ __forceinline__ float dpp_add(float x) {
    const int xi = __float_as_int(x);
    const int yi = __builtin_amdgcn_update_dpp(0, xi, CTRL, 0xF, 0xF, true);
    return x + __int_as_float(yi);
}

// ---------------------------------------------------------------- kernel 1
// broadcast raw slots -> out[0..393215] as float4.
// K*D = 6144 floats = 1536 float4 per b. 1536 is NOT a power of two -> use
// explicit div/mod by 6 blocks per b (6*256 = 1536). grid 384 x 256.
__global__ void k_broadcast(const float* __restrict__ slots, float* __restrict__ out) {
    const int b   = blockIdx.x / 6;
    const int r   = blockIdx.x % 6;
    const int idx = r * 256 + threadIdx.x;                 // 0..1535 (float4)
    reinterpret_cast<float4*>(out)[b * 1536 + idx] =
        reinterpret_cast<const float4*>(slots)[idx];
}

// ---------------------------------------------------------------- kernel 1b
// normalize slots -> ws snorm. grid 8 x 256
__global__ void k_snorm(const float* __restrict__ slots, float* __restrict__ snorm) {
    const int k = blockIdx.x;
    const int t = threadIdx.x;
    const int lane = t & 63, wave = t >> 6;
    __shared__ float wsum[4];
    float s = 0.f;
    for (int j = t; j < DD; j += 256) {
        float v = slots[k * DD + j];
        s += v * v;
    }
#pragma unroll
    for (int off = 1; off < 64; off <<= 1) s += __shfl_xor(s, off, 64);
    if (lane == 0) wsum[wave] = s;
    __syncthreads();
    const float tot = wsum[0] + wsum[1] + wsum[2] + wsum[3];
    const float rn = 1.0f / fmaxf(sqrtf(tot), 1e-6f);
    for (int j = t; j < DD; j += 256) snorm[k * DD + j] = slots[k * DD + j] * rn;
}

// ---------------------------------------------------------------- kernel 2
// logits[b][k][n] = dot(x[b,n,:], snorm[k,:]) / max(||x_n||, eps)
// grid 1024 blocks x 256 thr; b = blk>>4, chunk = blk&15 (64 n per chunk).
// wave handles 16 consecutive n; lane owns 12 d-elements (3 x float4);
// slots live in 96 loop-invariant VGPRs.
// Reduction (10 DS + 6 DPP per patch):
//   fold xor4  (split by b2): 8 accs -> 4   (4 shfl + selects), u: 1 shfl
//   fold xor16 (split by b4): 4 -> 2        (2 shfl),           u: 1 shfl
//   fold xor32 (split by b5): 2 -> 1        (1 shfl),           u: 1 shfl
//   xor1/xor2/xor8 via DPP on z,u           (6 VALU, no DS)
// final: lane holds total for k = 4*b2 + 2*b4 + b5; store from (lane&11)==0.
__launch_bounds__(256)
__global__ void k_logits(const float* __restrict__ x, const float* __restrict__ snorm,
                         float* __restrict__ logits) {
    const int b     = blockIdx.x >> 4;
    const int chunk = blockIdx.x & 15;
    const int wave  = threadIdx.x >> 6;
    const int lane  = threadIdx.x & 63;
    const int b2 = (lane >> 2) & 1, b4 = (lane >> 4) & 1, b5 = (lane >> 5) & 1;

    // loop-invariant slot fragments: sreg[k][j] = snorm[k, j*256 + lane*4 .. +3]
    float4 sreg[KK][3];
#pragma unroll
    for (int k = 0; k < KK; ++k)
#pragma unroll
        for (int j = 0; j < 3; ++j)
            sreg[k][j] = *reinterpret_cast<const float4*>(snorm + k * DD + j * 256 + lane * 4);

    const int n_base = chunk * 64 + wave * 16;

    auto compute_one = [&](int n, float4 c0, float4 c1, float4 c2) {
        float acc[KK];
#pragma unroll
        for (int q = 0; q < KK; ++q) acc[q] = 0.f;

#pragma unroll
        for (int k = 0; k < KK; ++k) {
            acc[k] = fmaf(c0.x, sreg[k][0].x, acc[k]);
            acc[k] = fmaf(c0.y, sreg[k][0].y, acc[k]);
            acc[k] = fmaf(c0.z, sreg[k][0].z, acc[k]);
            acc[k] = fmaf(c0.w, sreg[k][0].w, acc[k]);
            acc[k] = fmaf(c1.x, sreg[k][1].x, acc[k]);
            acc[k] = fmaf(c1.y, sreg[k][1].y, acc[k]);
            acc[k] = fmaf(c1.z, sreg[k][1].z, acc[k]);
            acc[k] = fmaf(c1.w, sreg[k][1].w, acc[k]);
            acc[k] = fmaf(c2.x, sreg[k][2].x, acc[k]);
            acc[k] = fmaf(c2.y, sreg[k][2].y, acc[k]);
            acc[k] = fmaf(c2.z, sreg[k][2].z, acc[k]);
            acc[k] = fmaf(c2.w, sreg[k][2].w, acc[k]);
        }
        float u = 0.f;
        u = fmaf(c0.x, c0.x, u); u = fmaf(c0.y, c0.y, u);
        u = fmaf(c0.z, c0.z, u); u = fmaf(c0.w, c0.w, u);
        u = fmaf(c1.x, c1.x, u); u = fmaf(c1.y, c1.y, u);
        u = fmaf(c1.z, c1.z, u); u = fmaf(c1.w, c1.w, u);
        u = fmaf(c2.x, c2.x, u); u = fmaf(c2.y, c2.y, u);
        u = fmaf(c2.z, c2.z, u); u = fmaf(c2.w, c2.w, u);

        // fold xor4: split k-set by b2 (b2=0 keeps k 0..3, sends 4..7)
        float w[4];
#pragma unroll
        for (int j = 0; j < 4; ++j) {
            const float send = b2 ? acc[j] : acc[j + 4];
            const float keep = b2 ? acc[j + 4] : acc[j];
            w[j] = keep + __shfl_xor(send, 4, 64);
        }
        u += __shfl_xor(u, 4, 64);

        // fold xor16: split by b4 (b4=0 keeps w0,w1; sends w2,w3)
        const float s0 = b4 ? w[0] : w[2];
        const float s1 = b4 ? w[1] : w[3];
        const float y0 = (b4 ? w[2] : w[0]) + __shfl_xor(s0, 16, 64);
        const float y1 = (b4 ? w[3] : w[1]) + __shfl_xor(s1, 16, 64);
        u += __shfl_xor(u, 16, 64);

        // fold xor32: split by b5 (b5=0 keeps y0, sends y1)
        const float sz = b5 ? y0 : y1;
        float z = (b5 ? y1 : y0) + __shfl_xor(sz, 32, 64);
        u += __shfl_xor(u, 32, 64);

        // cheap levels via DPP (VALU-only): xor1, xor2, xor8
        z = dpp_add<0xB1>(z);   u = dpp_add<0xB1>(u);
        z = dpp_add<0x4E>(z);   u = dpp_add<0x4E>(u);
        z = dpp_add<0x128>(z);  u = dpp_add<0x128>(u);

        const float rn = 1.0f / fmaxf(sqrtf(u), 1e-6f);
        if ((lane & 11) == 0) {                    // b0=b1=b3=0: 8 lanes, all k
            const int k = 4 * b2 + 2 * b4 + b5;
            logits[(((b << 3) + k) << 10) + n] = z * rn;
        }
    };

    // software pipeline: every body iteration prefetches unconditionally,
    // last iteration peeled.
    const float4* xrow = reinterpret_cast<const float4*>(x + (long)(b * NN + n_base) * DD);
    float4 c0 = xrow[lane], c1 = xrow[64 + lane], c2 = xrow[128 + lane];

    for (int i = 0; i < 15; ++i) {
        const float4* xq = xrow + (i + 1) * (DD / 4);
        float4 p0 = xq[lane], p1 = xq[64 + lane], p2 = xq[128 + lane];
        compute_one(n_base + i, c0, c1, c2);
        c0 = p0; c1 = p1; c2 = p2;
    }
    compute_one(n_base + 15, c0, c1, c2);
}

// ---------------------------------------------------------------- kernel 3
// per-b: top-8 thresholds, img_space_mask, exp rows, gram, ortho partial.
// grid 64 x 512 (8 waves; wave w owns row w).
__launch_bounds__(512)
__global__ void k_select(const float* __restrict__ logits, float* __restrict__ out_mask,
                         float* __restrict__ partials) {
    const int b = blockIdx.x;
    __shared__ float lds[KK][1032];   // padded rows (stride 1032 -> bank spread)
    __shared__ float thr[KK], rmax[KK], rsum[KK];
    __shared__ float gpart[8][64];
    const int t = threadIdx.x, lane = t & 63, wave = t >> 6;

    // A: load logits[b] (8 x 1024) into LDS
    for (int f = t; f < KK * NN; f += 512) lds[f >> 10][f & 1023] = logits[b * (KK * NN) + f];
    __syncthreads();

    // B: top-8 per row via 8x argmax-extract; wave w handles row w.
    {
        const int k = wave;
        float v[16];
#pragma unroll
        for (int i = 0; i < 16; ++i) v[i] = lds[k][i * 64 + lane];
        float th = 0.f, mx = -1e30f;
        for (int e = 0; e < 8; ++e) {
            float lv = -1e30f; int li = 0;
#pragma unroll
            for (int i = 0; i < 16; ++i) {
                if (v[i] > lv) { lv = v[i]; li = i * 64 + lane; }
            }
#pragma unroll
            for (int off = 1; off < 64; off <<= 1) {
                const float ov = __shfl_xor(lv, off, 64);
                const int   oi = __shfl_xor(li, off, 64);
                if (ov > lv || (ov == lv && oi < li)) { lv = ov; li = oi; }
            }
            if (e == 0) mx = lv;
            th = lv;
            // remove exactly the found instance (static indices only)
#pragma unroll
            for (int i = 0; i < 16; ++i)
                if (i * 64 + lane == li) v[i] = -1e30f;
        }
        if (lane == 0) { thr[k] = th; rmax[k] = mx; }
    }
    __syncthreads();

    // M: img_space_mask[b][n] = any_k(logit >= thr)
    for (int n = t; n < NN; n += 512) {
        float m = 0.f;
#pragma unroll
        for (int k = 0; k < KK; ++k) m = fmaxf(m, (lds[k][n] >= thr[k]) ? 1.f : 0.f);
        out_mask[b * NN + n] = m;
    }
    __syncthreads();

    // C: overwrite rows with exp(logit - rowmax) for selected, 0 otherwise; row sums.
    {
        const int k = wave;
        const float th = thr[k], mx = rmax[k];
        float s = 0.f;
#pragma unroll
        for (int i = 0; i < 16; ++i) {
            const int n = i * 64 + lane;
            const float lg = lds[k][n];
            const float p = (lg >= th) ? __expf(lg - mx) : 0.f;
            lds[k][n] = p;
            s += p;
        }
#pragma unroll
        for (int off = 1; off < 64; off <<= 1) s += __shfl_xor(s, off, 64);
        if (lane == 0) rsum[k] = s;
    }
    __syncthreads();

    // D: gram[k][j] = (sum_n p_k p_j) / (rsum_k rsum_j); partial ortho sum.
    {
        const int k = lane >> 3, j = lane & 7;
        float s = 0.f;
#pragma unroll 8
        for (int i = 0; i < 128; ++i) {
            const int n = (wave << 7) + i;
            s += lds[k][n] * lds[j][n];
        }
        gpart[wave][lane] = s;
    }
    __syncthreads();
    if (wave == 0) {
        const int k = lane >> 3, j = lane & 7;
        float g = 0.f;
#pragma unroll
        for (int w = 0; w < 8; ++w) g += gpart[w][lane];
        g *= (1.0f / rsum[k]) * (1.0f / rsum[j]);
        float d = fabsf(g - ((k == j) ? 1.f : 0.f));
#pragma unroll
        for (int off = 1; off < 64; off <<= 1) d += __shfl_xor(d, off, 64);
        if (lane == 0) partials[b] = d;
    }
}

// ---------------------------------------------------------------- kernel 4
__global__ void k_final(const float* __restrict__ partials, float* __restrict__ out_loss) {
    const int lane = threadIdx.x;  // 64
    float v = partials[lane];
#pragma unroll
    for (int off = 1; off < 64; off <<= 1) v += __shfl_xor(v, off, 64);
    if (lane == 0) out_loss[0] = v * (1.0f / 4096.0f);
}

extern "C" void kernel_launch(void* const* d_in, const int* in_sizes, int n_in,
                              void* d_out, int out_size, void* d_ws, size_t ws_size,
                              hipStream_t stream) {
    const float* x     = (const float*)d_in[0];   // (64,1024,768) f32
    const float* slots = (const float*)d_in[1];   // (1,8,768)     f32
    float* out = (float*)d_out;
    float* ws  = (float*)d_ws;

    float* snorm    = ws + WS_SNORM;
    float* logits   = ws + WS_LOGITS;
    float* partials = ws + WS_PART;

    float* out_slots = out;                         // 393216
    float* out_loss  = out + 393216;                // 1
    float* out_mask  = out + 393217;                // 65536

    k_broadcast<<<dim3(384),     dim3(256), 0, stream>>>(slots, out_slots);
    k_snorm    <<<dim3(KK),      dim3(256), 0, stream>>>(slots, snorm);
    k_logits   <<<dim3(BB * 16), dim3(256), 0, stream>>>(x, snorm, logits);
    k_select   <<<dim3(BB),      dim3(512), 0, stream>>>(logits, out_mask, partials);
    k_final    <<<dim3(1),       dim3(64),  0, stream>>>(partials, out_loss);
}